// Round 9
// baseline (211.963 us; speedup 1.0000x reference)
//
#include <hip/hip_runtime.h>
#include <hip/hip_bf16.h>

typedef __attribute__((ext_vector_type(8))) short bf16x8;
typedef __attribute__((ext_vector_type(4))) short bf16x4;
typedef __attribute__((ext_vector_type(4))) float f32x4;
typedef __attribute__((ext_vector_type(16))) float f32x16;
typedef __attribute__((ext_vector_type(4))) unsigned uint4v;

#define MFMA16(a, b, c) __builtin_amdgcn_mfma_f32_16x16x32_bf16(a, b, c, 0, 0, 0)
#define MFMA32(a, b, c) __builtin_amdgcn_mfma_f32_32x32x16_bf16(a, b, c, 0, 0, 0)

__device__ __forceinline__ unsigned short f2bfn(float f) {
#if defined(__gfx950__)
  __bf16 h = (__bf16)f;
  return __builtin_bit_cast(unsigned short, h);
#else
  union { float f; unsigned u; } x; x.f = f;
  unsigned r = x.u + 0x7fffu + ((x.u >> 16) & 1u);
  return (unsigned short)(r >> 16);
#endif
}

// swap a's upper 32 lanes with b's lower 32 lanes (compiler-managed permlane)
__device__ __forceinline__ void plswap(unsigned& a, unsigned& b) {
  auto r = __builtin_amdgcn_permlane32_swap(a, b, false, false);
  a = r[0];
  b = r[1];
}

__device__ __forceinline__ unsigned cvtpk(float lo, float hi) {
  unsigned w;
  asm("v_cvt_pk_bf16_f32 %0, %1, %2" : "=v"(w) : "v"(lo), "v"(hi));
  return w;
}

// ---------------- fp32 -> bf16 conversion (weights only) ----------------
__device__ __forceinline__ void cvt_body(const float* __restrict__ s,
                                         unsigned short* __restrict__ d, int n8) {
  int i = blockIdx.x * blockDim.x + threadIdx.x;
  int st = gridDim.x * blockDim.x;
  for (; i < n8; i += st) {
    const float4* sp = reinterpret_cast<const float4*>(s) + 2 * (size_t)i;
    float4 a = sp[0], b = sp[1];
    uint4v o;
    o[0] = cvtpk(a.x, a.y); o[1] = cvtpk(a.z, a.w);
    o[2] = cvtpk(b.x, b.y); o[3] = cvtpk(b.z, b.w);
    reinterpret_cast<uint4v*>(d)[i] = o;
  }
}

__global__ void cvt_w_kernel(const float* s0, const float* s1, const float* s2, const float* s3,
                             unsigned short* d0, unsigned short* d1, unsigned short* d2,
                             unsigned short* d3, int n8) {
  const float* s; unsigned short* d;
  switch (blockIdx.y) {
    case 0: s = s0; d = d0; break;
    case 1: s = s1; d = d1; break;
    case 2: s = s2; d = d2; break;
    default: s = s3; d = d3; break;
  }
  cvt_body(s, d, n8);
}

// ---------------- GEMM: out[m,n] = sum_k A[m,k]*B[n,k] + bias ----------------
// bf16 operands staged via global_load_lds (linear LDS, pre-swizzled source);
// fp32 operand staged via coalesced reg-load (2 consecutive float4/lane) +
// cvt_pk + swizzled ds_write after the MFMA phase (T14 split).
// MODE 0: A fp32 act, B bf16 w, bias[col], out bf16 scattered [B,H,S,64]
// MODE 1: A bf16,     B bf16 w, bias[col], out fp32 row-major [M,N]
// MODE 2: A bf16 w,   B fp32 act, bias[row], out bf16 V^T [BH,64,S]
template <int MODE>
__global__ __launch_bounds__(256) void gemm_kernel(
    const void* __restrict__ Av, const void* __restrict__ Bv,
    const float* __restrict__ bias, void* __restrict__ outv,
    int M, int N, int K) {
  constexpr bool AF32 = (MODE == 0);
  constexpr bool BF32 = (MODE == 2);
  constexpr int BM = 128, BN = 128, BK = 64;
  __shared__ __align__(16) unsigned short As[2][BM * BK];
  __shared__ __align__(16) unsigned short Bs[2][BN * BK];
  const int tid = threadIdx.x;
  const int lane = tid & 63, wave = tid >> 6;
  const int wr = wave >> 1, wc = wave & 1;
  const int m0 = blockIdx.y * BM, n0 = blockIdx.x * BN;
  const int rb = lane & 15, g = lane >> 4;
  const int swz = ((lane & 7) ^ ((lane >> 3) & 7)) * 8;
  f32x4 acc[4][4] = {};

  const unsigned short* Ab16 = (const unsigned short*)Av + (size_t)m0 * K;
  const unsigned short* Bb16 = (const unsigned short*)Bv + (size_t)n0 * K;
  const float* Ab32 = (const float*)Av + (size_t)m0 * K;
  const float* Bb32 = (const float*)Bv + (size_t)n0 * K;

  auto gload = [&](const unsigned short* base, unsigned short* dst, int k0) {
#pragma unroll
    for (int i = 0; i < 4; ++i) {
      const int c = wave * 256 + i * 64 + lane;  // 16B chunk, linear LDS
      const int r = c >> 3;
      __builtin_amdgcn_global_load_lds(
          (const __attribute__((address_space(1))) unsigned int*)(base + (size_t)r * K + k0 + swz),
          (__attribute__((address_space(3))) unsigned int*)&dst[c * 8], 16, 0, 0);
    }
  };
  // coalesced fp32 tile issue: chunk d = tid+256j -> row d>>3, 8-col chunk d&7;
  // each lane reads 32B contiguous; wave covers 8 dense 256B row-segments.
  auto f32issue = [&](const float* base, int k0, float4* v) {
#pragma unroll
    for (int j = 0; j < 4; ++j) {
      const int d = tid + 256 * j;
      const int r = d >> 3, ch = d & 7;
      const float* p = base + (size_t)r * K + k0 + ch * 8;
      v[2 * j] = *reinterpret_cast<const float4*>(p);
      v[2 * j + 1] = *reinterpret_cast<const float4*>(p + 4);
    }
  };
  auto f32write = [&](unsigned short* T, const float4* v) {
#pragma unroll
    for (int j = 0; j < 4; ++j) {
      const int d = tid + 256 * j;
      const int r = d >> 3, ch = d & 7;
      uint4v o;
      o[0] = cvtpk(v[2 * j].x, v[2 * j].y);
      o[1] = cvtpk(v[2 * j].z, v[2 * j].w);
      o[2] = cvtpk(v[2 * j + 1].x, v[2 * j + 1].y);
      o[3] = cvtpk(v[2 * j + 1].z, v[2 * j + 1].w);
      *reinterpret_cast<uint4v*>(&T[r * 64 + ((ch ^ (r & 7)) * 8)]) = o;
    }
  };

  const int nt = K / BK;
  // prologue: stage tile 0
  {
    float4 fv[8];
    if constexpr (AF32) {
      f32issue(Ab32, 0, fv);
      gload(Bb16, Bs[0], 0);
      f32write(As[0], fv);
    } else if constexpr (BF32) {
      f32issue(Bb32, 0, fv);
      gload(Ab16, As[0], 0);
      f32write(Bs[0], fv);
    } else {
      gload(Ab16, As[0], 0);
      gload(Bb16, Bs[0], 0);
    }
  }

  int cur = 0;
  for (int t = 0; t < nt; ++t) {
    __syncthreads();  // tile[t] ready
    const bool more = (t + 1 < nt);
    const int k1 = (t + 1) * BK;
    float4 nv[8];
    if (more) {
      if constexpr (AF32) {
        gload(Bb16, Bs[cur ^ 1], k1);
        f32issue(Ab32, k1, nv);
      } else if constexpr (BF32) {
        gload(Ab16, As[cur ^ 1], k1);
        f32issue(Bb32, k1, nv);
      } else {
        gload(Ab16, As[cur ^ 1], k1);
        gload(Bb16, Bs[cur ^ 1], k1);
      }
    }
    const unsigned short* A_ = As[cur];
    const unsigned short* B_ = Bs[cur];
#pragma unroll
    for (int kc = 0; kc < 2; ++kc) {
      bf16x8 af[4], bfr[4];
#pragma unroll
      for (int mi = 0; mi < 4; ++mi)
        af[mi] = *reinterpret_cast<const bf16x8*>(
            &A_[(wr * 64 + mi * 16 + rb) * 64 + (((kc * 4 + g) ^ (rb & 7)) * 8)]);
#pragma unroll
      for (int ni = 0; ni < 4; ++ni)
        bfr[ni] = *reinterpret_cast<const bf16x8*>(
            &B_[(wc * 64 + ni * 16 + rb) * 64 + (((kc * 4 + g) ^ (rb & 7)) * 8)]);
#pragma unroll
      for (int mi = 0; mi < 4; ++mi)
#pragma unroll
        for (int ni = 0; ni < 4; ++ni)
          acc[mi][ni] = MFMA16(af[mi], bfr[ni], acc[mi][ni]);
    }
    if (more) {
      if constexpr (AF32) f32write(As[cur ^ 1], nv);
      if constexpr (BF32) f32write(Bs[cur ^ 1], nv);
    }
    cur ^= 1;
  }

#pragma unroll
  for (int mi = 0; mi < 4; ++mi) {
#pragma unroll
    for (int ni = 0; ni < 4; ++ni) {
      int col = n0 + wc * 64 + ni * 16 + rb;
      if constexpr (MODE != 2) {
        float bv = bias[col];
#pragma unroll
        for (int j = 0; j < 4; ++j) {
          int row = m0 + wr * 64 + mi * 16 + g * 4 + j;
          float v = acc[mi][ni][j] + bv;
          if constexpr (MODE == 0) {
            int b = row >> 11, s = row & 2047;
            int h = col >> 6, e = col & 63;
            ((unsigned short*)outv)[((size_t)(b * 16 + h) * 2048 + s) * 64 + e] = f2bfn(v);
          } else {
            ((float*)outv)[(size_t)row * N + col] = v;
          }
        }
      } else {
        int bb = col >> 11, s = col & 2047;
#pragma unroll
        for (int j = 0; j < 4; ++j) {
          int row = m0 + wr * 64 + mi * 16 + g * 4 + j;
          float v = acc[mi][ni][j] + bias[row];
          int h = row >> 6, e = row & 63;
          ((unsigned short*)outv)[((size_t)(bb * 16 + h) * 64 + e) * 2048 + s] = f2bfn(v);
        }
      }
    }
  }
}

// ---------------- flash attention: 32x32 swapped, NO-MAX in-register softmax ----------------
// Q,K: bf16 [B*H, S, 64]; Vt: bf16 [B*H, 64, S]; ctx out: bf16 [B, S, H*64]
// qti permutation balances per-CU work: every CU's 4 resident blocks (stride-256
// dispatch) have qti summing 30 -> 68 block-iters on every CU.
__global__ __launch_bounds__(256) void attn5_kernel(
    const unsigned short* __restrict__ Qp, const unsigned short* __restrict__ Kp,
    const unsigned short* __restrict__ Vtp, unsigned short* __restrict__ ctx) {
  constexpr int S = 2048;
  __shared__ __align__(16) unsigned short Ks[2][64 * 64];
  __shared__ __align__(16) unsigned short Vs[2][64 * 64];
  const int qtimap16[16] = {15, 13, 11, 9, 0, 2, 4, 6, 14, 12, 10, 8, 1, 3, 5, 7};
  const int bx = blockIdx.x;
  const int bh = bx & 63;
  const int qti = qtimap16[bx >> 6];
  const int q0 = qti * 128;
  const int tid = threadIdx.x, wave = tid >> 6, lane = tid & 63;
  const int l31 = lane & 31, hb = lane >> 5, hb4 = hb * 4;
  const int x7 = l31 & 7;  // read-side XOR swizzle key
  const int qw = q0 + wave * 32;
  const unsigned short* Qb = Qp + (size_t)bh * S * 64;
  const unsigned short* Kb = Kp + (size_t)bh * S * 64;
  const unsigned short* Vb = Vtp + (size_t)bh * 64 * S;

  // Q B-fragments: lane holds Q[qw+l31][16kc+8hb .. +7]
  bf16x8 qg[4];
#pragma unroll
  for (int kc = 0; kc < 4; ++kc)
    qg[kc] = *reinterpret_cast<const bf16x8*>(
        Qb + (size_t)(qw + l31) * 64 + 16 * kc + 8 * hb);

  float lsum = 0.f;
  f32x16 o[2] = {};
  const float sc = 0.03125f * 1.4426950408889634f;  // 1/sqrt(1024) * log2(e)
  const float SH = -2.0f;  // constant shift (cancels in normalization)
  const int sswz = ((lane & 7) ^ (lane >> 3)) * 8;  // staging source pre-swizzle
  const int nt = qti * 2 + 2;

  auto stage = [&](int buf, int kv0) {
#pragma unroll
    for (int i = 0; i < 2; ++i) {
      const int ci = (wave * 2 + i) * 64 + lane;       // 16B chunk (linear LDS)
      const int r = (wave * 2 + i) * 8 + (lane >> 3);  // tile row
      __builtin_amdgcn_global_load_lds(
          (const __attribute__((address_space(1))) unsigned int*)(Kb + (size_t)(kv0 + r) * 64 + sswz),
          (__attribute__((address_space(3))) unsigned int*)&Ks[buf][ci * 8], 16, 0, 0);
      __builtin_amdgcn_global_load_lds(
          (const __attribute__((address_space(1))) unsigned int*)(Vb + (size_t)r * S + kv0 + sswz),
          (__attribute__((address_space(3))) unsigned int*)&Vs[buf][ci * 8], 16, 0, 0);
    }
  };

  stage(0, 0);

  for (int it = 0; it < nt; ++it) {
    __syncthreads();  // staged tile [it] ready (drains vmcnt)
    if (it + 1 < nt) stage((it + 1) & 1, 64 * (it + 1));
    const int kv0 = 64 * it;
    if (kv0 <= qw + 31) {
      const unsigned short* K_ = Ks[it & 1];
      const unsigned short* V_ = Vs[it & 1];
      // ---- S^T = K Q^T: lane owns q-col = qw + l31; k rows in regs ----
      f32x16 sacc[2] = {};
      __builtin_amdgcn_s_setprio(1);
#pragma unroll
      for (int kc = 0; kc < 4; ++kc) {
        bf16x8 kf0 = *reinterpret_cast<const bf16x8*>(
            &K_[l31 * 64 + ((2 * kc + hb) ^ x7) * 8]);
        bf16x8 kf1 = *reinterpret_cast<const bf16x8*>(
            &K_[(32 + l31) * 64 + ((2 * kc + hb) ^ x7) * 8]);
        sacc[0] = MFMA32(kf0, qg[kc], sacc[0]);
        sacc[1] = MFMA32(kf1, qg[kc], sacc[1]);
      }
      __builtin_amdgcn_s_setprio(0);
      // ---- causal mask (diag tiles only): k = kv0+32mi+(r&3)+8(r>>2)+hb4 ----
      if (kv0 + 63 > qw) {
        const int qrel = qw + l31 - kv0;
#pragma unroll
        for (int mi = 0; mi < 2; ++mi)
#pragma unroll
          for (int r = 0; r < 16; ++r) {
            int koff = 32 * mi + (r & 3) + 8 * (r >> 2) + hb4;
            if (koff > qrel) sacc[mi][r] = -1e30f;
          }
      }
      // ---- P = exp2(fma(s,sc,SH)); pack to bf16 pairs; tree row-sum ----
      float p0[16], p1[16];
#pragma unroll
      for (int r = 0; r < 16; ++r)
        p0[r] = __builtin_amdgcn_exp2f(fmaf(sacc[0][r], sc, SH));
#pragma unroll
      for (int r = 0; r < 16; ++r)
        p1[r] = __builtin_amdgcn_exp2f(fmaf(sacc[1][r], sc, SH));
      unsigned pw[2][8];
#pragma unroll
      for (int i = 0; i < 8; ++i) pw[0][i] = cvtpk(p0[2 * i], p0[2 * i + 1]);
#pragma unroll
      for (int i = 0; i < 8; ++i) pw[1][i] = cvtpk(p1[2 * i], p1[2 * i + 1]);
      float a[16];
#pragma unroll
      for (int r = 0; r < 16; ++r) a[r] = p0[r] + p1[r];
#pragma unroll
      for (int s = 8; s > 0; s >>= 1)
#pragma unroll
        for (int r = 0; r < s; ++r) a[r] += a[r + s];
      lsum += a[0];  // per-lane half-sum; combined across lane^32 at epilogue
      // ---- assemble PV B-frags: lane needs k = 16c + 8hb + 0..7 ----
#pragma unroll
      for (int mi = 0; mi < 2; ++mi) {
        plswap(pw[mi][0], pw[mi][2]);
        plswap(pw[mi][1], pw[mi][3]);
        plswap(pw[mi][4], pw[mi][6]);
        plswap(pw[mi][5], pw[mi][7]);
      }
      // ---- O^T += V^T P^T ----
      __builtin_amdgcn_s_setprio(1);
#pragma unroll
      for (int c = 0; c < 4; ++c) {
        union { unsigned u[4]; bf16x8 v; } pu;
        pu.u[0] = pw[c >> 1][(c & 1) * 4 + 0];
        pu.u[1] = pw[c >> 1][(c & 1) * 4 + 1];
        pu.u[2] = pw[c >> 1][(c & 1) * 4 + 2];
        pu.u[3] = pw[c >> 1][(c & 1) * 4 + 3];
#pragma unroll
        for (int db = 0; db < 2; ++db) {
          bf16x8 vf = *reinterpret_cast<const bf16x8*>(
              &V_[(32 * db + l31) * 64 + ((2 * c + hb) ^ x7) * 8]);
          o[db] = MFMA32(vf, pu.v, o[db]);
        }
      }
      __builtin_amdgcn_s_setprio(0);
    }
  }

  // ---- epilogue: lane holds O^T[d = 32db+(r&3)+8(r>>2)+hb4][q = qw+l31] ----
  const float tot = lsum + __shfl_xor(lsum, 32, 64);
  const float inv = 1.0f / tot;
  const int b = bh >> 4, h = bh & 15;
  const int q = qw + l31;
  unsigned short* cp = ctx + ((size_t)(b * 2048 + q) * 1024) + h * 64;
#pragma unroll
  for (int db = 0; db < 2; ++db)
#pragma unroll
    for (int i = 0; i < 8; ++i) {
      unsigned w = cvtpk(o[db][2 * i] * inv, o[db][2 * i + 1] * inv);
      int d = 32 * db + ((2 * i) & 3) + 8 * (i >> 1) + hb4;
      *reinterpret_cast<unsigned*>(cp + d) = w;
    }
}

extern "C" void kernel_launch(void* const* d_in, const int* in_sizes, int n_in,
                              void* d_out, int out_size, void* d_ws, size_t ws_size,
                              hipStream_t stream) {
  const float* in_q = (const float*)d_in[0];
  const float* in_k = (const float*)d_in[1];
  const float* in_v = (const float*)d_in[2];
  const float* WQw = (const float*)d_in[3];
  const float* WQb = (const float*)d_in[4];
  const float* WKw = (const float*)d_in[5];
  const float* WKb = (const float*)d_in[6];
  const float* WVw = (const float*)d_in[7];
  const float* WVb = (const float*)d_in[8];
  const float* Ww  = (const float*)d_in[9];
  const float* Wb  = (const float*)d_in[10];
  float* out = (float*)d_out;

  constexpr size_t PROJ = (size_t)4 * 16 * 2048 * 64;  // 8,388,608 elems
  constexpr size_t WSZ = (size_t)1024 * 1024;
  unsigned short* wsp = (unsigned short*)d_ws;
  unsigned short* Qp   = wsp;
  unsigned short* Kp   = wsp + PROJ;
  unsigned short* Vt   = wsp + 2 * PROJ;
  unsigned short* ctx  = wsp + 3 * PROJ;
  unsigned short* wq16 = wsp + 4 * PROJ;
  unsigned short* wk16 = wq16 + WSZ;
  unsigned short* wv16 = wk16 + WSZ;
  unsigned short* ww16 = wv16 + WSZ;

  // weights -> bf16 (batched)
  cvt_w_kernel<<<dim3(256, 4), 256, 0, stream>>>(WQw, WKw, WVw, Ww,
                                                 wq16, wk16, wv16, ww16, (int)(WSZ / 8));
  // Q,K projections (fp32 A, fused cvt in staging) -> [B,H,S,64] bf16
  gemm_kernel<0><<<dim3(8, 64), 256, 0, stream>>>(in_q, wq16, WQb, Qp, 8192, 1024, 1024);
  gemm_kernel<0><<<dim3(8, 64), 256, 0, stream>>>(in_k, wk16, WKb, Kp, 8192, 1024, 1024);
  // V projection computed transposed (fp32 B, fused cvt) -> V^T [B*H, 64, S]
  gemm_kernel<2><<<dim3(64, 8), 256, 0, stream>>>(wv16, in_v, WVb, Vt, 1024, 8192, 1024);

  // flash attention -> ctx [B,S,1024] bf16 (1024 blocks, per-CU-balanced qti)
  attn5_kernel<<<1024, 256, 0, stream>>>(Qp, Kp, Vt, ctx);

  // output projection -> fp32
  gemm_kernel<1><<<dim3(8, 64), 256, 0, stream>>>(ctx, ww16, Wb, out, 8192, 1024, 1024);
}

// Round 10
// 206.175 us; speedup vs baseline: 1.0281x; 1.0281x over previous
//
#include <hip/hip_runtime.h>
#include <hip/hip_bf16.h>

typedef __attribute__((ext_vector_type(8))) short bf16x8;
typedef __attribute__((ext_vector_type(4))) short bf16x4;
typedef __attribute__((ext_vector_type(4))) float f32x4;
typedef __attribute__((ext_vector_type(16))) float f32x16;
typedef __attribute__((ext_vector_type(4))) unsigned uint4v;

#define MFMA16(a, b, c) __builtin_amdgcn_mfma_f32_16x16x32_bf16(a, b, c, 0, 0, 0)
#define MFMA32(a, b, c) __builtin_amdgcn_mfma_f32_32x32x16_bf16(a, b, c, 0, 0, 0)

__device__ __forceinline__ unsigned short f2bfn(float f) {
#if defined(__gfx950__)
  __bf16 h = (__bf16)f;
  return __builtin_bit_cast(unsigned short, h);
#else
  union { float f; unsigned u; } x; x.f = f;
  unsigned r = x.u + 0x7fffu + ((x.u >> 16) & 1u);
  return (unsigned short)(r >> 16);
#endif
}

// swap a's upper 32 lanes with b's lower 32 lanes (compiler-managed permlane)
__device__ __forceinline__ void plswap(unsigned& a, unsigned& b) {
  auto r = __builtin_amdgcn_permlane32_swap(a, b, false, false);
  a = r[0];
  b = r[1];
}

__device__ __forceinline__ unsigned cvtpk(float lo, float hi) {
  unsigned w;
  asm("v_cvt_pk_bf16_f32 %0, %1, %2" : "=v"(w) : "v"(lo), "v"(hi));
  return w;
}

// ---------------- fp32 -> bf16 conversion ----------------
__device__ __forceinline__ void cvt_body(const float* __restrict__ s,
                                         unsigned short* __restrict__ d, int n8) {
  int i = blockIdx.x * blockDim.x + threadIdx.x;
  int st = gridDim.x * blockDim.x;
  for (; i < n8; i += st) {
    const float4* sp = reinterpret_cast<const float4*>(s) + 2 * (size_t)i;
    float4 a = sp[0], b = sp[1];
    uint4v o;
    o[0] = cvtpk(a.x, a.y); o[1] = cvtpk(a.z, a.w);
    o[2] = cvtpk(b.x, b.y); o[3] = cvtpk(b.z, b.w);
    reinterpret_cast<uint4v*>(d)[i] = o;
  }
}

__global__ void cvt1_kernel(const float* __restrict__ s, unsigned short* __restrict__ d, int n8) {
  cvt_body(s, d, n8);
}

__global__ void cvt_w_kernel(const float* s0, const float* s1, const float* s2, const float* s3,
                             unsigned short* d0, unsigned short* d1, unsigned short* d2,
                             unsigned short* d3, int n8) {
  const float* s; unsigned short* d;
  switch (blockIdx.y) {
    case 0: s = s0; d = d0; break;
    case 1: s = s1; d = d1; break;
    case 2: s = s2; d = d2; break;
    default: s = s3; d = d3; break;
  }
  cvt_body(s, d, n8);
}

// ---------------- GEMM: out[m,n] = sum_k A[m,k]*B[n,k] + bias ----------------
// All operands bf16 [rows, K] row-major. global_load_lds staging, XOR-swizzled
// LDS, double-buffered. BK=32 -> 32 KB LDS -> 4 blocks/CU (TLP hides the
// per-iter barrier drain; launch_bounds caps VGPR at 128).
// Bank layout: 64B rows; swizzle key (row>>1)&3 -> <=2-way conflicts (free).
// MODE 0: bias[col], out bf16 scattered [B,H,S,64]
// MODE 1: bias[col], out fp32 row-major [M,N]
// MODE 2: bias[row], out bf16 V^T layout [BH,64,S]
template <int MODE>
__global__ __launch_bounds__(256, 4) void gemm_kernel(
    const unsigned short* __restrict__ Av, const unsigned short* __restrict__ Bv,
    const float* __restrict__ bias, void* __restrict__ outv,
    int M, int N, int K) {
  constexpr int BM = 128, BN = 128, BK = 32;
  __shared__ __align__(16) unsigned short As[2][BM * BK];
  __shared__ __align__(16) unsigned short Bs[2][BN * BK];
  const int tid = threadIdx.x;
  const int lane = tid & 63, wave = tid >> 6;
  const int wr = wave >> 1, wc = wave & 1;
  const int m0 = blockIdx.y * BM, n0 = blockIdx.x * BN;
  const int rb = lane & 15, g = lane >> 4;
  // staging source pre-swizzle: chunk ch=lane&3, row key (r>>1)&3 = (lane>>3)&3
  const int swz = ((lane & 3) ^ ((lane >> 3) & 3)) * 8;
  const int rk = (rb >> 1) & 3;  // read-side key for row wr*64+mi*16+rb
  f32x4 acc[4][4] = {};

  const unsigned short* Ab = Av + (size_t)m0 * K;
  const unsigned short* Bb = Bv + (size_t)n0 * K;

  auto stage = [&](int buf, int k0) {
#pragma unroll
    for (int i = 0; i < 2; ++i) {
      const int c = wave * 128 + i * 64 + lane;  // 16B chunk, linear LDS
      const int r = c >> 2;                      // tile row (4 chunks/row)
      __builtin_amdgcn_global_load_lds(
          (const __attribute__((address_space(1))) unsigned int*)(Ab + (size_t)r * K + k0 + swz),
          (__attribute__((address_space(3))) unsigned int*)&As[buf][c * 8], 16, 0, 0);
      __builtin_amdgcn_global_load_lds(
          (const __attribute__((address_space(1))) unsigned int*)(Bb + (size_t)r * K + k0 + swz),
          (__attribute__((address_space(3))) unsigned int*)&Bs[buf][c * 8], 16, 0, 0);
    }
  };

  const int nt = K / BK;
  stage(0, 0);
  int cur = 0;
  for (int t = 0; t < nt; ++t) {
    __syncthreads();  // tile[t] staged
    if (t + 1 < nt) stage(cur ^ 1, (t + 1) * BK);
    const unsigned short* A_ = As[cur];
    const unsigned short* B_ = Bs[cur];
    bf16x8 af[4], bfr[4];
#pragma unroll
    for (int mi = 0; mi < 4; ++mi)
      af[mi] = *reinterpret_cast<const bf16x8*>(
          &A_[(wr * 64 + mi * 16 + rb) * 32 + ((g ^ rk) * 8)]);
#pragma unroll
    for (int ni = 0; ni < 4; ++ni)
      bfr[ni] = *reinterpret_cast<const bf16x8*>(
          &B_[(wc * 64 + ni * 16 + rb) * 32 + ((g ^ rk) * 8)]);
#pragma unroll
    for (int mi = 0; mi < 4; ++mi)
#pragma unroll
      for (int ni = 0; ni < 4; ++ni)
        acc[mi][ni] = MFMA16(af[mi], bfr[ni], acc[mi][ni]);
    cur ^= 1;
  }

#pragma unroll
  for (int mi = 0; mi < 4; ++mi) {
#pragma unroll
    for (int ni = 0; ni < 4; ++ni) {
      int col = n0 + wc * 64 + ni * 16 + rb;
      if constexpr (MODE != 2) {
        float bv = bias[col];
#pragma unroll
        for (int j = 0; j < 4; ++j) {
          int row = m0 + wr * 64 + mi * 16 + g * 4 + j;
          float v = acc[mi][ni][j] + bv;
          if constexpr (MODE == 0) {
            int b = row >> 11, s = row & 2047;
            int h = col >> 6, e = col & 63;
            ((unsigned short*)outv)[((size_t)(b * 16 + h) * 2048 + s) * 64 + e] = f2bfn(v);
          } else {
            ((float*)outv)[(size_t)row * N + col] = v;
          }
        }
      } else {
        int bb = col >> 11, s = col & 2047;
#pragma unroll
        for (int j = 0; j < 4; ++j) {
          int row = m0 + wr * 64 + mi * 16 + g * 4 + j;
          float v = acc[mi][ni][j] + bias[row];
          int h = row >> 6, e = row & 63;
          ((unsigned short*)outv)[((size_t)(bb * 16 + h) * 64 + e) * 2048 + s] = f2bfn(v);
        }
      }
    }
  }
}

// ---------------- flash attention: 32x32 swapped, NO-MAX in-register softmax ----------------
// (round-8 proven config: 1024 blocks, heavy-first, 2-buffer, 69.2 us)
__global__ __launch_bounds__(256) void attn5_kernel(
    const unsigned short* __restrict__ Qp, const unsigned short* __restrict__ Kp,
    const unsigned short* __restrict__ Vtp, unsigned short* __restrict__ ctx) {
  constexpr int S = 2048;
  __shared__ __align__(16) unsigned short Ks[2][64 * 64];
  __shared__ __align__(16) unsigned short Vs[2][64 * 64];
  const int bx = blockIdx.x;
  const int bh = bx & 63;
  const int qti = 15 - (bx >> 6);  // heavy tiles first
  const int q0 = qti * 128;
  const int tid = threadIdx.x, wave = tid >> 6, lane = tid & 63;
  const int l31 = lane & 31, hb = lane >> 5, hb4 = hb * 4;
  const int x7 = l31 & 7;  // read-side XOR swizzle key
  const int qw = q0 + wave * 32;
  const unsigned short* Qb = Qp + (size_t)bh * S * 64;
  const unsigned short* Kb = Kp + (size_t)bh * S * 64;
  const unsigned short* Vb = Vtp + (size_t)bh * 64 * S;

  bf16x8 qg[4];
#pragma unroll
  for (int kc = 0; kc < 4; ++kc)
    qg[kc] = *reinterpret_cast<const bf16x8*>(
        Qb + (size_t)(qw + l31) * 64 + 16 * kc + 8 * hb);

  float lsum = 0.f;
  f32x16 o[2] = {};
  const float sc = 0.03125f * 1.4426950408889634f;  // 1/sqrt(1024) * log2(e)
  const float SH = -2.0f;  // constant shift (cancels in normalization)
  const int sswz = ((lane & 7) ^ (lane >> 3)) * 8;  // staging source pre-swizzle
  const int nt = qti * 2 + 2;

  auto stage = [&](int buf, int kv0) {
#pragma unroll
    for (int i = 0; i < 2; ++i) {
      const int ci = (wave * 2 + i) * 64 + lane;       // 16B chunk (linear LDS)
      const int r = (wave * 2 + i) * 8 + (lane >> 3);  // tile row
      __builtin_amdgcn_global_load_lds(
          (const __attribute__((address_space(1))) unsigned int*)(Kb + (size_t)(kv0 + r) * 64 + sswz),
          (__attribute__((address_space(3))) unsigned int*)&Ks[buf][ci * 8], 16, 0, 0);
      __builtin_amdgcn_global_load_lds(
          (const __attribute__((address_space(1))) unsigned int*)(Vb + (size_t)r * S + kv0 + sswz),
          (__attribute__((address_space(3))) unsigned int*)&Vs[buf][ci * 8], 16, 0, 0);
    }
  };

  stage(0, 0);

  for (int it = 0; it < nt; ++it) {
    __syncthreads();  // staged tile [it] ready (drains vmcnt)
    if (it + 1 < nt) stage((it + 1) & 1, 64 * (it + 1));
    const int kv0 = 64 * it;
    if (kv0 <= qw + 31) {
      const unsigned short* K_ = Ks[it & 1];
      const unsigned short* V_ = Vs[it & 1];
      // ---- S^T = K Q^T: lane owns q-col = qw + l31; k rows in regs ----
      f32x16 sacc[2] = {};
      __builtin_amdgcn_s_setprio(1);
#pragma unroll
      for (int kc = 0; kc < 4; ++kc) {
        bf16x8 kf0 = *reinterpret_cast<const bf16x8*>(
            &K_[l31 * 64 + ((2 * kc + hb) ^ x7) * 8]);
        bf16x8 kf1 = *reinterpret_cast<const bf16x8*>(
            &K_[(32 + l31) * 64 + ((2 * kc + hb) ^ x7) * 8]);
        sacc[0] = MFMA32(kf0, qg[kc], sacc[0]);
        sacc[1] = MFMA32(kf1, qg[kc], sacc[1]);
      }
      __builtin_amdgcn_s_setprio(0);
      // ---- causal mask (diag tiles only): k = kv0+32mi+(r&3)+8(r>>2)+hb4 ----
      if (kv0 + 63 > qw) {
        const int qrel = qw + l31 - kv0;
#pragma unroll
        for (int mi = 0; mi < 2; ++mi)
#pragma unroll
          for (int r = 0; r < 16; ++r) {
            int koff = 32 * mi + (r & 3) + 8 * (r >> 2) + hb4;
            if (koff > qrel) sacc[mi][r] = -1e30f;
          }
      }
      // ---- P = exp2(fma(s,sc,SH)); pack to bf16 pairs; tree row-sum ----
      float p0[16], p1[16];
#pragma unroll
      for (int r = 0; r < 16; ++r)
        p0[r] = __builtin_amdgcn_exp2f(fmaf(sacc[0][r], sc, SH));
#pragma unroll
      for (int r = 0; r < 16; ++r)
        p1[r] = __builtin_amdgcn_exp2f(fmaf(sacc[1][r], sc, SH));
      unsigned pw[2][8];
#pragma unroll
      for (int i = 0; i < 8; ++i) pw[0][i] = cvtpk(p0[2 * i], p0[2 * i + 1]);
#pragma unroll
      for (int i = 0; i < 8; ++i) pw[1][i] = cvtpk(p1[2 * i], p1[2 * i + 1]);
      float a[16];
#pragma unroll
      for (int r = 0; r < 16; ++r) a[r] = p0[r] + p1[r];
#pragma unroll
      for (int s = 8; s > 0; s >>= 1)
#pragma unroll
        for (int r = 0; r < s; ++r) a[r] += a[r + s];
      lsum += a[0];  // per-lane half-sum; combined across lane^32 at epilogue
      // ---- assemble PV B-frags: lane needs k = 16c + 8hb + 0..7 ----
#pragma unroll
      for (int mi = 0; mi < 2; ++mi) {
        plswap(pw[mi][0], pw[mi][2]);
        plswap(pw[mi][1], pw[mi][3]);
        plswap(pw[mi][4], pw[mi][6]);
        plswap(pw[mi][5], pw[mi][7]);
      }
      // ---- O^T += V^T P^T ----
      __builtin_amdgcn_s_setprio(1);
#pragma unroll
      for (int c = 0; c < 4; ++c) {
        union { unsigned u[4]; bf16x8 v; } pu;
        pu.u[0] = pw[c >> 1][(c & 1) * 4 + 0];
        pu.u[1] = pw[c >> 1][(c & 1) * 4 + 1];
        pu.u[2] = pw[c >> 1][(c & 1) * 4 + 2];
        pu.u[3] = pw[c >> 1][(c & 1) * 4 + 3];
#pragma unroll
        for (int db = 0; db < 2; ++db) {
          bf16x8 vf = *reinterpret_cast<const bf16x8*>(
              &V_[(32 * db + l31) * 64 + ((2 * c + hb) ^ x7) * 8]);
          o[db] = MFMA32(vf, pu.v, o[db]);
        }
      }
      __builtin_amdgcn_s_setprio(0);
    }
  }

  // ---- epilogue: lane holds O^T[d = 32db+(r&3)+8(r>>2)+hb4][q = qw+l31] ----
  const float tot = lsum + __shfl_xor(lsum, 32, 64);
  const float inv = 1.0f / tot;
  const int b = bh >> 4, h = bh & 15;
  const int q = qw + l31;
  unsigned short* cp = ctx + ((size_t)(b * 2048 + q) * 1024) + h * 64;
#pragma unroll
  for (int db = 0; db < 2; ++db)
#pragma unroll
    for (int i = 0; i < 8; ++i) {
      unsigned w = cvtpk(o[db][2 * i] * inv, o[db][2 * i + 1] * inv);
      int d = 32 * db + ((2 * i) & 3) + 8 * (i >> 1) + hb4;
      *reinterpret_cast<unsigned*>(cp + d) = w;
    }
}

extern "C" void kernel_launch(void* const* d_in, const int* in_sizes, int n_in,
                              void* d_out, int out_size, void* d_ws, size_t ws_size,
                              hipStream_t stream) {
  const float* in_q = (const float*)d_in[0];
  const float* in_k = (const float*)d_in[1];
  const float* in_v = (const float*)d_in[2];
  const float* WQw = (const float*)d_in[3];
  const float* WQb = (const float*)d_in[4];
  const float* WKw = (const float*)d_in[5];
  const float* WKb = (const float*)d_in[6];
  const float* WVw = (const float*)d_in[7];
  const float* WVb = (const float*)d_in[8];
  const float* Ww  = (const float*)d_in[9];
  const float* Wb  = (const float*)d_in[10];
  float* out = (float*)d_out;

  constexpr size_t PROJ = (size_t)4 * 16 * 2048 * 64;  // 8,388,608 elems
  constexpr size_t WSZ = (size_t)1024 * 1024;
  unsigned short* wsp = (unsigned short*)d_ws;
  unsigned short* Qp   = wsp;
  unsigned short* Kp   = wsp + PROJ;
  unsigned short* Vt   = wsp + 2 * PROJ;
  unsigned short* in16 = wsp + 3 * PROJ;  // reused q->k->v, then aliased as ctx
  unsigned short* ctx  = in16;
  unsigned short* wq16 = wsp + 4 * PROJ;
  unsigned short* wk16 = wq16 + WSZ;
  unsigned short* wv16 = wk16 + WSZ;
  unsigned short* ww16 = wv16 + WSZ;

  // weights -> bf16 (batched)
  cvt_w_kernel<<<dim3(256, 4), 256, 0, stream>>>(WQw, WKw, WVw, Ww,
                                                 wq16, wk16, wv16, ww16, (int)(WSZ / 8));
  // Q projection
  cvt1_kernel<<<2048, 256, 0, stream>>>(in_q, in16, (int)(PROJ / 8));
  gemm_kernel<0><<<dim3(8, 64), 256, 0, stream>>>(in16, wq16, WQb, Qp, 8192, 1024, 1024);
  // K projection
  cvt1_kernel<<<2048, 256, 0, stream>>>(in_k, in16, (int)(PROJ / 8));
  gemm_kernel<0><<<dim3(8, 64), 256, 0, stream>>>(in16, wk16, WKb, Kp, 8192, 1024, 1024);
  // V projection, computed transposed -> V^T [B*H, 64, S]
  cvt1_kernel<<<2048, 256, 0, stream>>>(in_v, in16, (int)(PROJ / 8));
  gemm_kernel<2><<<dim3(64, 8), 256, 0, stream>>>(wv16, in16, WVb, Vt, 1024, 8192, 1024);

  // flash attention -> ctx [B,S,1024] bf16 (1024 blocks, heavy-first)
  attn5_kernel<<<1024, 256, 0, stream>>>(Qp, Kp, Vt, ctx);

  // output projection -> fp32
  gemm_kernel<1><<<dim3(8, 64), 256, 0, stream>>>(ctx, ww16, Wb, out, 8192, 1024, 1024);
}

// Round 11
// 190.097 us; speedup vs baseline: 1.1150x; 1.0846x over previous
//
#include <hip/hip_runtime.h>
#include <hip/hip_bf16.h>

typedef __attribute__((ext_vector_type(8))) short bf16x8;
typedef __attribute__((ext_vector_type(4))) short bf16x4;
typedef __attribute__((ext_vector_type(4))) float f32x4;
typedef __attribute__((ext_vector_type(16))) float f32x16;
typedef __attribute__((ext_vector_type(4))) unsigned uint4v;

#define MFMA16(a, b, c) __builtin_amdgcn_mfma_f32_16x16x32_bf16(a, b, c, 0, 0, 0)
#define MFMA32(a, b, c) __builtin_amdgcn_mfma_f32_32x32x16_bf16(a, b, c, 0, 0, 0)

__device__ __forceinline__ unsigned short f2bfn(float f) {
#if defined(__gfx950__)
  __bf16 h = (__bf16)f;
  return __builtin_bit_cast(unsigned short, h);
#else
  union { float f; unsigned u; } x; x.f = f;
  unsigned r = x.u + 0x7fffu + ((x.u >> 16) & 1u);
  return (unsigned short)(r >> 16);
#endif
}

// swap a's upper 32 lanes with b's lower 32 lanes (compiler-managed permlane)
__device__ __forceinline__ void plswap(unsigned& a, unsigned& b) {
  auto r = __builtin_amdgcn_permlane32_swap(a, b, false, false);
  a = r[0];
  b = r[1];
}

__device__ __forceinline__ unsigned cvtpk(float lo, float hi) {
  unsigned w;
  asm("v_cvt_pk_bf16_f32 %0, %1, %2" : "=v"(w) : "v"(lo), "v"(hi));
  return w;
}

// ---------------- fp32 -> bf16 conversion ----------------
__device__ __forceinline__ void cvt_body(const float* __restrict__ s,
                                         unsigned short* __restrict__ d, int n8) {
  int i = blockIdx.x * blockDim.x + threadIdx.x;
  int st = gridDim.x * blockDim.x;
  for (; i < n8; i += st) {
    const float4* sp = reinterpret_cast<const float4*>(s) + 2 * (size_t)i;
    float4 a = sp[0], b = sp[1];
    uint4v o;
    o[0] = cvtpk(a.x, a.y); o[1] = cvtpk(a.z, a.w);
    o[2] = cvtpk(b.x, b.y); o[3] = cvtpk(b.z, b.w);
    reinterpret_cast<uint4v*>(d)[i] = o;
  }
}

__global__ void cvt1_kernel(const float* __restrict__ s, unsigned short* __restrict__ d, int n8) {
  cvt_body(s, d, n8);
}

__global__ void cvt_w_kernel(const float* s0, const float* s1, const float* s2, const float* s3,
                             unsigned short* d0, unsigned short* d1, unsigned short* d2,
                             unsigned short* d3, int n8) {
  const float* s; unsigned short* d;
  switch (blockIdx.y) {
    case 0: s = s0; d = d0; break;
    case 1: s = s1; d = d1; break;
    case 2: s = s2; d = d2; break;
    default: s = s3; d = d3; break;
  }
  cvt_body(s, d, n8);
}

// ---------------- GEMM: out[m,n] = (sum_k A[m,k]*B[n,k] + bias) * oscale ----------------
// All operands bf16 [rows, K] row-major. global_load_lds staging, XOR-swizzled
// LDS, double-buffered, 1 barrier/iter.  (round-4/8 proven config, ~23 us)
// MODE 0: bias[col], out bf16 scattered [B,H,S,64]; oscale applied (softmax
//         scale folded into Q projection)
// MODE 1: bias[col], out fp32 row-major [M,N]
// MODE 2: bias[row], out bf16 V^T layout [BH,64,S]
template <int MODE>
__global__ __launch_bounds__(256) void gemm_kernel(
    const unsigned short* __restrict__ Av, const unsigned short* __restrict__ Bv,
    const float* __restrict__ bias, void* __restrict__ outv,
    int M, int N, int K, float oscale) {
  constexpr int BM = 128, BN = 128, BK = 64;
  __shared__ __align__(16) unsigned short As[2][BM * BK];
  __shared__ __align__(16) unsigned short Bs[2][BN * BK];
  const int tid = threadIdx.x;
  const int lane = tid & 63, wave = tid >> 6;
  const int wr = wave >> 1, wc = wave & 1;
  const int m0 = blockIdx.y * BM, n0 = blockIdx.x * BN;
  const int rb = lane & 15, g = lane >> 4;
  const int swz = ((lane & 7) ^ ((lane >> 3) & 7)) * 8;
  f32x4 acc[4][4] = {};

  const unsigned short* Ab = Av + (size_t)m0 * K;
  const unsigned short* Bb = Bv + (size_t)n0 * K;

  auto stage = [&](int buf, int k0) {
#pragma unroll
    for (int i = 0; i < 4; ++i) {
      const int c = wave * 256 + i * 64 + lane;
      const int r = c >> 3;
      __builtin_amdgcn_global_load_lds(
          (const __attribute__((address_space(1))) unsigned int*)(Ab + (size_t)r * K + k0 + swz),
          (__attribute__((address_space(3))) unsigned int*)&As[buf][c * 8], 16, 0, 0);
      __builtin_amdgcn_global_load_lds(
          (const __attribute__((address_space(1))) unsigned int*)(Bb + (size_t)r * K + k0 + swz),
          (__attribute__((address_space(3))) unsigned int*)&Bs[buf][c * 8], 16, 0, 0);
    }
  };

  const int nt = K / BK;
  stage(0, 0);
  int cur = 0;
  for (int t = 0; t < nt; ++t) {
    __syncthreads();
    if (t + 1 < nt) stage(cur ^ 1, (t + 1) * BK);
    const unsigned short* A_ = As[cur];
    const unsigned short* B_ = Bs[cur];
#pragma unroll
    for (int kc = 0; kc < 2; ++kc) {
      bf16x8 af[4], bfr[4];
#pragma unroll
      for (int mi = 0; mi < 4; ++mi)
        af[mi] = *reinterpret_cast<const bf16x8*>(
            &A_[(wr * 64 + mi * 16 + rb) * 64 + (((kc * 4 + g) ^ (rb & 7)) * 8)]);
#pragma unroll
      for (int ni = 0; ni < 4; ++ni)
        bfr[ni] = *reinterpret_cast<const bf16x8*>(
            &B_[(wc * 64 + ni * 16 + rb) * 64 + (((kc * 4 + g) ^ (rb & 7)) * 8)]);
#pragma unroll
      for (int mi = 0; mi < 4; ++mi)
#pragma unroll
        for (int ni = 0; ni < 4; ++ni)
          acc[mi][ni] = MFMA16(af[mi], bfr[ni], acc[mi][ni]);
    }
    cur ^= 1;
  }

#pragma unroll
  for (int mi = 0; mi < 4; ++mi) {
#pragma unroll
    for (int ni = 0; ni < 4; ++ni) {
      int col = n0 + wc * 64 + ni * 16 + rb;
      if constexpr (MODE != 2) {
        float bv = bias[col];
#pragma unroll
        for (int j = 0; j < 4; ++j) {
          int row = m0 + wr * 64 + mi * 16 + g * 4 + j;
          float v = acc[mi][ni][j] + bv;
          if constexpr (MODE == 0) {
            v *= oscale;
            int b = row >> 11, s = row & 2047;
            int h = col >> 6, e = col & 63;
            ((unsigned short*)outv)[((size_t)(b * 16 + h) * 2048 + s) * 64 + e] = f2bfn(v);
          } else {
            ((float*)outv)[(size_t)row * N + col] = v;
          }
        }
      } else {
        int bb = col >> 11, s = col & 2047;
#pragma unroll
        for (int j = 0; j < 4; ++j) {
          int row = m0 + wr * 64 + mi * 16 + g * 4 + j;
          float v = acc[mi][ni][j] + bias[row];
          int h = row >> 6, e = row & 63;
          ((unsigned short*)outv)[((size_t)(bb * 16 + h) * 64 + e) * 2048 + s] = f2bfn(v);
        }
      }
    }
  }
}

// ---------------- flash attention: 32x32 swapped, NO-MAX softmax, MFMA row-sum ----------------
// Q (PRE-SCALED by 1/sqrt(1024)*log2e in projection), K: bf16 [B*H, S, 64];
// Vt: bf16 [B*H, 64, S]; ctx out: bf16 [B, S, H*64]
// P = exp2(sacc) directly off the MFMA result; row-sum accumulated by a
// ones-A MFMA32 on the same P B-fragments PV consumes (no VALU tree, no
// cross-half shuffle: the MFMA sums the full K including both lane halves).
__global__ __launch_bounds__(256) void attn6_kernel(
    const unsigned short* __restrict__ Qp, const unsigned short* __restrict__ Kp,
    const unsigned short* __restrict__ Vtp, unsigned short* __restrict__ ctx) {
  constexpr int S = 2048;
  __shared__ __align__(16) unsigned short Ks[2][64 * 64];
  __shared__ __align__(16) unsigned short Vs[2][64 * 64];
  const int bx = blockIdx.x;
  const int bh = bx & 63;
  const int qti = 15 - (bx >> 6);  // heavy tiles first
  const int q0 = qti * 128;
  const int tid = threadIdx.x, wave = tid >> 6, lane = tid & 63;
  const int l31 = lane & 31, hb = lane >> 5, hb4 = hb * 4;
  const int x7 = l31 & 7;  // read-side XOR swizzle key
  const int qw = q0 + wave * 32;
  const unsigned short* Qb = Qp + (size_t)bh * S * 64;
  const unsigned short* Kb = Kp + (size_t)bh * S * 64;
  const unsigned short* Vb = Vtp + (size_t)bh * 64 * S;

  bf16x8 qg[4];
#pragma unroll
  for (int kc = 0; kc < 4; ++kc)
    qg[kc] = *reinterpret_cast<const bf16x8*>(
        Qb + (size_t)(qw + l31) * 64 + 16 * kc + 8 * hb);

  bf16x8 ones;
#pragma unroll
  for (int i = 0; i < 8; ++i) ones[i] = (short)0x3F80;  // bf16 1.0

  f32x16 ls = {};  // row-sum accumulator (all 16 regs identical)
  f32x16 o[2] = {};
  const int sswz = ((lane & 7) ^ (lane >> 3)) * 8;  // staging source pre-swizzle
  const int nt = qti * 2 + 2;

  auto stage = [&](int buf, int kv0) {
#pragma unroll
    for (int i = 0; i < 2; ++i) {
      const int ci = (wave * 2 + i) * 64 + lane;       // 16B chunk (linear LDS)
      const int r = (wave * 2 + i) * 8 + (lane >> 3);  // tile row
      __builtin_amdgcn_global_load_lds(
          (const __attribute__((address_space(1))) unsigned int*)(Kb + (size_t)(kv0 + r) * 64 + sswz),
          (__attribute__((address_space(3))) unsigned int*)&Ks[buf][ci * 8], 16, 0, 0);
      __builtin_amdgcn_global_load_lds(
          (const __attribute__((address_space(1))) unsigned int*)(Vb + (size_t)r * S + kv0 + sswz),
          (__attribute__((address_space(3))) unsigned int*)&Vs[buf][ci * 8], 16, 0, 0);
    }
  };

  stage(0, 0);

  for (int it = 0; it < nt; ++it) {
    __syncthreads();  // staged tile [it] ready (drains vmcnt)
    if (it + 1 < nt) stage((it + 1) & 1, 64 * (it + 1));
    const int kv0 = 64 * it;
    if (kv0 <= qw + 31) {
      const unsigned short* K_ = Ks[it & 1];
      const unsigned short* V_ = Vs[it & 1];
      // ---- S^T = K Q^T (pre-scaled): lane owns q-col = qw + l31 ----
      f32x16 sacc[2] = {};
      __builtin_amdgcn_s_setprio(1);
#pragma unroll
      for (int kc = 0; kc < 4; ++kc) {
        bf16x8 kf0 = *reinterpret_cast<const bf16x8*>(
            &K_[l31 * 64 + ((2 * kc + hb) ^ x7) * 8]);
        bf16x8 kf1 = *reinterpret_cast<const bf16x8*>(
            &K_[(32 + l31) * 64 + ((2 * kc + hb) ^ x7) * 8]);
        sacc[0] = MFMA32(kf0, qg[kc], sacc[0]);
        sacc[1] = MFMA32(kf1, qg[kc], sacc[1]);
      }
      __builtin_amdgcn_s_setprio(0);
      // ---- causal mask (diag tiles only): k = kv0+32mi+(r&3)+8(r>>2)+hb4 ----
      if (kv0 + 63 > qw) {
        const int qrel = qw + l31 - kv0;
#pragma unroll
        for (int mi = 0; mi < 2; ++mi)
#pragma unroll
          for (int r = 0; r < 16; ++r) {
            int koff = 32 * mi + (r & 3) + 8 * (r >> 2) + hb4;
            if (koff > qrel) sacc[mi][r] = -1e30f;
          }
      }
      // ---- P = exp2(sacc) directly (logits pre-scaled; masked -> 0) ----
      float p0[16], p1[16];
#pragma unroll
      for (int r = 0; r < 16; ++r) p0[r] = __builtin_amdgcn_exp2f(sacc[0][r]);
#pragma unroll
      for (int r = 0; r < 16; ++r) p1[r] = __builtin_amdgcn_exp2f(sacc[1][r]);
      unsigned pw[2][8];
#pragma unroll
      for (int i = 0; i < 8; ++i) pw[0][i] = cvtpk(p0[2 * i], p0[2 * i + 1]);
#pragma unroll
      for (int i = 0; i < 8; ++i) pw[1][i] = cvtpk(p1[2 * i], p1[2 * i + 1]);
      // ---- assemble PV B-frags: lane needs k = 16c + 8hb + 0..7 ----
#pragma unroll
      for (int mi = 0; mi < 2; ++mi) {
        plswap(pw[mi][0], pw[mi][2]);
        plswap(pw[mi][1], pw[mi][3]);
        plswap(pw[mi][4], pw[mi][6]);
        plswap(pw[mi][5], pw[mi][7]);
      }
      // ---- O^T += V^T P^T ; row-sum += ones * P^T (same B-frags) ----
      __builtin_amdgcn_s_setprio(1);
#pragma unroll
      for (int c = 0; c < 4; ++c) {
        union { unsigned u[4]; bf16x8 v; } pu;
        pu.u[0] = pw[c >> 1][(c & 1) * 4 + 0];
        pu.u[1] = pw[c >> 1][(c & 1) * 4 + 1];
        pu.u[2] = pw[c >> 1][(c & 1) * 4 + 2];
        pu.u[3] = pw[c >> 1][(c & 1) * 4 + 3];
#pragma unroll
        for (int db = 0; db < 2; ++db) {
          bf16x8 vf = *reinterpret_cast<const bf16x8*>(
              &V_[(32 * db + l31) * 64 + ((2 * c + hb) ^ x7) * 8]);
          o[db] = MFMA32(vf, pu.v, o[db]);
        }
        ls = MFMA32(ones, pu.v, ls);
      }
      __builtin_amdgcn_s_setprio(0);
    }
  }

  // ---- epilogue: lane holds O^T[d = 32db+(r&3)+8(r>>2)+hb4][q = qw+l31] ----
  // ls regs all equal the FULL row-sum for q (MFMA summed across both halves).
  const float inv = 1.0f / ls[0];
  const int b = bh >> 4, h = bh & 15;
  const int q = qw + l31;
  unsigned short* cp = ctx + ((size_t)(b * 2048 + q) * 1024) + h * 64;
#pragma unroll
  for (int db = 0; db < 2; ++db)
#pragma unroll
    for (int i = 0; i < 8; ++i) {
      unsigned w = cvtpk(o[db][2 * i] * inv, o[db][2 * i + 1] * inv);
      int d = 32 * db + ((2 * i) & 3) + 8 * (i >> 1) + hb4;
      *reinterpret_cast<unsigned*>(cp + d) = w;
    }
}

extern "C" void kernel_launch(void* const* d_in, const int* in_sizes, int n_in,
                              void* d_out, int out_size, void* d_ws, size_t ws_size,
                              hipStream_t stream) {
  const float* in_q = (const float*)d_in[0];
  const float* in_k = (const float*)d_in[1];
  const float* in_v = (const float*)d_in[2];
  const float* WQw = (const float*)d_in[3];
  const float* WQb = (const float*)d_in[4];
  const float* WKw = (const float*)d_in[5];
  const float* WKb = (const float*)d_in[6];
  const float* WVw = (const float*)d_in[7];
  const float* WVb = (const float*)d_in[8];
  const float* Ww  = (const float*)d_in[9];
  const float* Wb  = (const float*)d_in[10];
  float* out = (float*)d_out;

  constexpr size_t PROJ = (size_t)4 * 16 * 2048 * 64;  // 8,388,608 elems
  constexpr size_t WSZ = (size_t)1024 * 1024;
  unsigned short* wsp = (unsigned short*)d_ws;
  unsigned short* Qp   = wsp;
  unsigned short* Kp   = wsp + PROJ;
  unsigned short* Vt   = wsp + 2 * PROJ;
  unsigned short* in16 = wsp + 3 * PROJ;  // reused q->k->v, then aliased as ctx
  unsigned short* ctx  = in16;
  unsigned short* wq16 = wsp + 4 * PROJ;
  unsigned short* wk16 = wq16 + WSZ;
  unsigned short* wv16 = wk16 + WSZ;
  unsigned short* ww16 = wv16 + WSZ;

  const float qscale = 0.03125f * 1.4426950408889634f;  // 1/sqrt(1024) * log2(e)

  // weights -> bf16 (batched)
  cvt_w_kernel<<<dim3(256, 4), 256, 0, stream>>>(WQw, WKw, WVw, Ww,
                                                 wq16, wk16, wv16, ww16, (int)(WSZ / 8));
  // Q projection (pre-scaled by qscale)
  cvt1_kernel<<<2048, 256, 0, stream>>>(in_q, in16, (int)(PROJ / 8));
  gemm_kernel<0><<<dim3(8, 64), 256, 0, stream>>>(in16, wq16, WQb, Qp, 8192, 1024, 1024, qscale);
  // K projection
  cvt1_kernel<<<2048, 256, 0, stream>>>(in_k, in16, (int)(PROJ / 8));
  gemm_kernel<0><<<dim3(8, 64), 256, 0, stream>>>(in16, wk16, WKb, Kp, 8192, 1024, 1024, 1.0f);
  // V projection, computed transposed -> V^T [B*H, 64, S]
  cvt1_kernel<<<2048, 256, 0, stream>>>(in_v, in16, (int)(PROJ / 8));
  gemm_kernel<2><<<dim3(64, 8), 256, 0, stream>>>(wv16, in16, WVb, Vt, 1024, 8192, 1024, 1.0f);

  // flash attention -> ctx [B,S,1024] bf16 (1024 blocks, heavy-first)
  attn6_kernel<<<1024, 256, 0, stream>>>(Qp, Kp, Vt, ctx);

  // output projection -> fp32
  gemm_kernel<1><<<dim3(8, 64), 256, 0, stream>>>(ctx, ww16, Wb, out, 8192, 1024, 1024, 1.0f);
}

// Round 12
// 184.005 us; speedup vs baseline: 1.1519x; 1.0331x over previous
//
#include <hip/hip_runtime.h>
#include <hip/hip_bf16.h>

typedef __attribute__((ext_vector_type(8))) short bf16x8;
typedef __attribute__((ext_vector_type(4))) float f32x4;
typedef __attribute__((ext_vector_type(16))) float f32x16;
typedef __attribute__((ext_vector_type(4))) unsigned uint4v;

#define MFMA16(a, b, c) __builtin_amdgcn_mfma_f32_16x16x32_bf16(a, b, c, 0, 0, 0)
#define MFMA32(a, b, c) __builtin_amdgcn_mfma_f32_32x32x16_bf16(a, b, c, 0, 0, 0)

__device__ __forceinline__ unsigned short f2bfn(float f) {
#if defined(__gfx950__)
  __bf16 h = (__bf16)f;
  return __builtin_bit_cast(unsigned short, h);
#else
  union { float f; unsigned u; } x; x.f = f;
  unsigned r = x.u + 0x7fffu + ((x.u >> 16) & 1u);
  return (unsigned short)(r >> 16);
#endif
}

__device__ __forceinline__ unsigned cvtpk(float lo, float hi) {
  unsigned w;
  asm("v_cvt_pk_bf16_f32 %0, %1, %2" : "=v"(w) : "v"(lo), "v"(hi));
  return w;
}

// ---------------- fp32 -> bf16 conversion ----------------
__device__ __forceinline__ void cvt_range(const float* __restrict__ s,
                                          unsigned short* __restrict__ d,
                                          int i, int st, int n8) {
  for (; i < n8; i += st) {
    const float4* sp = reinterpret_cast<const float4*>(s) + 2 * (size_t)i;
    float4 a = sp[0], b = sp[1];
    uint4v o;
    o[0] = cvtpk(a.x, a.y); o[1] = cvtpk(a.z, a.w);
    o[2] = cvtpk(b.x, b.y); o[3] = cvtpk(b.z, b.w);
    reinterpret_cast<uint4v*>(d)[i] = o;
  }
}

__global__ void cvt1_kernel(const float* __restrict__ s, unsigned short* __restrict__ d, int n8) {
  cvt_range(s, d, blockIdx.x * blockDim.x + threadIdx.x, gridDim.x * blockDim.x, n8);
}

// y<4: weight matrices; y==4: Q input (larger, grid-strided)
__global__ void cvt_first_kernel(const float* s0, const float* s1, const float* s2,
                                 const float* s3, unsigned short* d0, unsigned short* d1,
                                 unsigned short* d2, unsigned short* d3, int wn8,
                                 const float* sq, unsigned short* dq, int qn8) {
  const float* s; unsigned short* d; int n8;
  switch (blockIdx.y) {
    case 0: s = s0; d = d0; n8 = wn8; break;
    case 1: s = s1; d = d1; n8 = wn8; break;
    case 2: s = s2; d = d2; n8 = wn8; break;
    case 3: s = s3; d = d3; n8 = wn8; break;
    default: s = sq; d = dq; n8 = qn8; break;
  }
  cvt_range(s, d, blockIdx.x * blockDim.x + threadIdx.x, gridDim.x * blockDim.x, n8);
}

// ---------------- GEMM: out[m,n] = (sum_k A[m,k]*B[n,k] + bias) * oscale ----------------
// bf16 operands, global_load_lds staging, XOR-swizzled LDS, double-buffered,
// 1 barrier/iter (round-4/8 proven config). 1D grid: n = bx & (2^nshift-1),
// m = bx >> nshift. Blocks with bx >= ngemm run an independent fp32->bf16
// conversion instead (hides the next projection's cvt under this GEMM).
// MODE 0: bias[col], out bf16 scattered [B,H,S,64], oscale applied
// MODE 1: bias[col], out fp32 row-major [M,N]
// MODE 2: bias[row], out bf16 V^T layout [BH,64,S]
template <int MODE>
__global__ __launch_bounds__(256) void gemm_kernel(
    const unsigned short* __restrict__ Av, const unsigned short* __restrict__ Bv,
    const float* __restrict__ bias, void* __restrict__ outv,
    int M, int N, int K, float oscale, int nshift, int ngemm,
    const float* __restrict__ csrc, unsigned short* __restrict__ cdst, int cn8) {
  constexpr int BM = 128, BN = 128, BK = 64;
  __shared__ __align__(16) unsigned short As[2][BM * BK];
  __shared__ __align__(16) unsigned short Bs[2][BN * BK];
  const int bx = blockIdx.x;
  const int tid = threadIdx.x;
  if (bx >= ngemm) {  // piggybacked cvt blocks
    cvt_range(csrc, cdst, (bx - ngemm) * blockDim.x + tid,
              (gridDim.x - ngemm) * blockDim.x, cn8);
    return;
  }
  const int lane = tid & 63, wave = tid >> 6;
  const int wr = wave >> 1, wc = wave & 1;
  const int m0 = (bx >> nshift) * BM, n0 = (bx & ((1 << nshift) - 1)) * BN;
  const int rb = lane & 15, g = lane >> 4;
  const int swz = ((lane & 7) ^ ((lane >> 3) & 7)) * 8;
  f32x4 acc[4][4] = {};

  const unsigned short* Ab = Av + (size_t)m0 * K;
  const unsigned short* Bb = Bv + (size_t)n0 * K;

  auto stage = [&](int buf, int k0) {
#pragma unroll
    for (int i = 0; i < 4; ++i) {
      const int c = wave * 256 + i * 64 + lane;
      const int r = c >> 3;
      __builtin_amdgcn_global_load_lds(
          (const __attribute__((address_space(1))) unsigned int*)(Ab + (size_t)r * K + k0 + swz),
          (__attribute__((address_space(3))) unsigned int*)&As[buf][c * 8], 16, 0, 0);
      __builtin_amdgcn_global_load_lds(
          (const __attribute__((address_space(1))) unsigned int*)(Bb + (size_t)r * K + k0 + swz),
          (__attribute__((address_space(3))) unsigned int*)&Bs[buf][c * 8], 16, 0, 0);
    }
  };

  const int nt = K / BK;
  stage(0, 0);
  int cur = 0;
  for (int t = 0; t < nt; ++t) {
    __syncthreads();
    if (t + 1 < nt) stage(cur ^ 1, (t + 1) * BK);
    const unsigned short* A_ = As[cur];
    const unsigned short* B_ = Bs[cur];
#pragma unroll
    for (int kc = 0; kc < 2; ++kc) {
      bf16x8 af[4], bfr[4];
#pragma unroll
      for (int mi = 0; mi < 4; ++mi)
        af[mi] = *reinterpret_cast<const bf16x8*>(
            &A_[(wr * 64 + mi * 16 + rb) * 64 + (((kc * 4 + g) ^ (rb & 7)) * 8)]);
#pragma unroll
      for (int ni = 0; ni < 4; ++ni)
        bfr[ni] = *reinterpret_cast<const bf16x8*>(
            &B_[(wc * 64 + ni * 16 + rb) * 64 + (((kc * 4 + g) ^ (rb & 7)) * 8)]);
#pragma unroll
      for (int mi = 0; mi < 4; ++mi)
#pragma unroll
        for (int ni = 0; ni < 4; ++ni)
          acc[mi][ni] = MFMA16(af[mi], bfr[ni], acc[mi][ni]);
    }
    cur ^= 1;
  }

#pragma unroll
  for (int mi = 0; mi < 4; ++mi) {
#pragma unroll
    for (int ni = 0; ni < 4; ++ni) {
      int col = n0 + wc * 64 + ni * 16 + rb;
      if constexpr (MODE != 2) {
        float bv = bias[col];
#pragma unroll
        for (int j = 0; j < 4; ++j) {
          int row = m0 + wr * 64 + mi * 16 + g * 4 + j;
          float v = acc[mi][ni][j] + bv;
          if constexpr (MODE == 0) {
            v *= oscale;
            int b = row >> 11, s = row & 2047;
            int h = col >> 6, e = col & 63;
            ((unsigned short*)outv)[((size_t)(b * 16 + h) * 2048 + s) * 64 + e] = f2bfn(v);
          } else {
            ((float*)outv)[(size_t)row * N + col] = v;
          }
        }
      } else {
        int bb = col >> 11, s = col & 2047;
#pragma unroll
        for (int j = 0; j < 4; ++j) {
          int row = m0 + wr * 64 + mi * 16 + g * 4 + j;
          float v = acc[mi][ni][j] + bias[row];
          int h = row >> 6, e = row & 63;
          ((unsigned short*)outv)[((size_t)(bb * 16 + h) * 64 + e) * 2048 + s] = f2bfn(v);
        }
      }
    }
  }
}

// ---------------- flash attention: 32x32 swapped, NO-MAX softmax, MFMA row-sum,
// K rows stored bit2<->bit3-swizzled in LDS so QK^T output lands exactly where
// PV's B-fragment consumes it: zero cross-lane ops (plswaps eliminated). ----------------
// Q (PRE-SCALED by 1/sqrt(1024)*log2e), K: bf16 [B*H, S, 64]; Vt: bf16 [B*H, 64, S]
__global__ __launch_bounds__(256) void attn7_kernel(
    const unsigned short* __restrict__ Qp, const unsigned short* __restrict__ Kp,
    const unsigned short* __restrict__ Vtp, unsigned short* __restrict__ ctx) {
  constexpr int S = 2048;
  __shared__ __align__(16) unsigned short Ks[2][64 * 64];
  __shared__ __align__(16) unsigned short Vs[2][64 * 64];
  const int bx = blockIdx.x;
  const int bh = bx & 63;
  const int qti = 15 - (bx >> 6);  // heavy tiles first
  const int tid = threadIdx.x, wave = tid >> 6, lane = tid & 63;
  const int l31 = lane & 31, hb = lane >> 5;
  const int x7 = l31 & 7;  // read-side XOR swizzle key
  const int qw = qti * 128 + wave * 32;
  const unsigned short* Qb = Qp + (size_t)bh * S * 64;
  const unsigned short* Kb = Kp + (size_t)bh * S * 64;
  const unsigned short* Vb = Vtp + (size_t)bh * 64 * S;

  bf16x8 qg[4];
#pragma unroll
  for (int kc = 0; kc < 4; ++kc)
    qg[kc] = *reinterpret_cast<const bf16x8*>(
        Qb + (size_t)(qw + l31) * 64 + 16 * kc + 8 * hb);

  bf16x8 ones;
#pragma unroll
  for (int i = 0; i < 8; ++i) ones[i] = (short)0x3F80;  // bf16 1.0

  f32x16 ls = {};  // row-sum accumulator (ones-MFMA; all regs = full row-sum)
  f32x16 o[2] = {};
  const int sswz = ((lane & 7) ^ (lane >> 3)) * 8;  // staging source pre-swizzle
  const int nt = qti * 2 + 2;

  // staging coords; K source row bit2<->bit3 swapped (swap23)
  const int ci0 = wave * 2 * 64 + lane, ci1 = ci0 + 64;
  const int r0 = wave * 16 + (lane >> 3), r1 = r0 + 8;
  const int rs0 = (r0 & 51) | ((r0 & 4) << 1) | ((r0 & 8) >> 1);
  const int rs1 = (r1 & 51) | ((r1 & 4) << 1) | ((r1 & 8) >> 1);
  const unsigned short* ks0 = Kb + (size_t)rs0 * 64 + sswz;
  const unsigned short* ks1 = Kb + (size_t)rs1 * 64 + sswz;
  const unsigned short* vs0 = Vb + (size_t)r0 * S + sswz;
  const unsigned short* vs1 = Vb + (size_t)r1 * S + sswz;

  auto stage = [&](int buf) {
    __builtin_amdgcn_global_load_lds(
        (const __attribute__((address_space(1))) unsigned int*)ks0,
        (__attribute__((address_space(3))) unsigned int*)&Ks[buf][ci0 * 8], 16, 0, 0);
    __builtin_amdgcn_global_load_lds(
        (const __attribute__((address_space(1))) unsigned int*)ks1,
        (__attribute__((address_space(3))) unsigned int*)&Ks[buf][ci1 * 8], 16, 0, 0);
    __builtin_amdgcn_global_load_lds(
        (const __attribute__((address_space(1))) unsigned int*)vs0,
        (__attribute__((address_space(3))) unsigned int*)&Vs[buf][ci0 * 8], 16, 0, 0);
    __builtin_amdgcn_global_load_lds(
        (const __attribute__((address_space(1))) unsigned int*)vs1,
        (__attribute__((address_space(3))) unsigned int*)&Vs[buf][ci1 * 8], 16, 0, 0);
    ks0 += 4096; ks1 += 4096;  // +64 K-rows
    vs0 += 64; vs1 += 64;      // +64 kv-cols
  };

  stage(0);

  for (int it = 0; it < nt; ++it) {
    __syncthreads();  // staged tile [it] ready (drains vmcnt)
    if (it + 1 < nt) stage((it + 1) & 1);
    const int kv0 = 64 * it;
    if (kv0 <= qw + 31) {
      const unsigned short* K_ = Ks[it & 1];
      const unsigned short* V_ = Vs[it & 1];
      // ---- S^T = K Q^T (pre-scaled, K rows swap23-permuted) ----
      f32x16 sacc[2] = {};
      __builtin_amdgcn_s_setprio(1);
#pragma unroll
      for (int kc = 0; kc < 4; ++kc) {
        bf16x8 kf0 = *reinterpret_cast<const bf16x8*>(
            &K_[l31 * 64 + ((2 * kc + hb) ^ x7) * 8]);
        bf16x8 kf1 = *reinterpret_cast<const bf16x8*>(
            &K_[(32 + l31) * 64 + ((2 * kc + hb) ^ x7) * 8]);
        sacc[0] = MFMA32(kf0, qg[kc], sacc[0]);
        sacc[1] = MFMA32(kf1, qg[kc], sacc[1]);
      }
      __builtin_amdgcn_s_setprio(0);
      // ---- causal mask (diag tiles): k = kv0 + (r&7) + 16*(r>>3) + 8hb + 32mi ----
      if (kv0 + 63 > qw) {
        const int qrel = qw + l31 - kv0 - 8 * hb;
#pragma unroll
        for (int mi = 0; mi < 2; ++mi)
#pragma unroll
          for (int r = 0; r < 16; ++r) {
            int koff = (r & 7) + 16 * (r >> 3) + 32 * mi;
            if (koff > qrel) sacc[mi][r] = -1e30f;
          }
      }
      // ---- P = exp2(sacc); pack to bf16; B-frags are ready as-is ----
      float p0[16], p1[16];
#pragma unroll
      for (int r = 0; r < 16; ++r) p0[r] = __builtin_amdgcn_exp2f(sacc[0][r]);
#pragma unroll
      for (int r = 0; r < 16; ++r) p1[r] = __builtin_amdgcn_exp2f(sacc[1][r]);
      unsigned pw[2][8];
#pragma unroll
      for (int i = 0; i < 8; ++i) pw[0][i] = cvtpk(p0[2 * i], p0[2 * i + 1]);
#pragma unroll
      for (int i = 0; i < 8; ++i) pw[1][i] = cvtpk(p1[2 * i], p1[2 * i + 1]);
      // ---- O^T += V^T P^T ; row-sum += ones * P^T ----
      __builtin_amdgcn_s_setprio(1);
#pragma unroll
      for (int c = 0; c < 4; ++c) {
        union { unsigned u[4]; bf16x8 v; } pu;
        pu.u[0] = pw[c >> 1][(c & 1) * 4 + 0];
        pu.u[1] = pw[c >> 1][(c & 1) * 4 + 1];
        pu.u[2] = pw[c >> 1][(c & 1) * 4 + 2];
        pu.u[3] = pw[c >> 1][(c & 1) * 4 + 3];
#pragma unroll
        for (int db = 0; db < 2; ++db) {
          bf16x8 vf = *reinterpret_cast<const bf16x8*>(
              &V_[(32 * db + l31) * 64 + ((2 * c + hb) ^ x7) * 8]);
          o[db] = MFMA32(vf, pu.v, o[db]);
        }
        ls = MFMA32(ones, pu.v, ls);
      }
      __builtin_amdgcn_s_setprio(0);
    }
  }

  // ---- epilogue: lane holds O^T[d = 32db+(r&3)+8(r>>2)+4hb][q = qw+l31] ----
  const float inv = 1.0f / ls[0];
  const int b = bh >> 4, h = bh & 15;
  const int q = qw + l31;
  unsigned short* cp = ctx + ((size_t)(b * 2048 + q) * 1024) + h * 64;
#pragma unroll
  for (int db = 0; db < 2; ++db)
#pragma unroll
    for (int i = 0; i < 8; ++i) {
      unsigned w = cvtpk(o[db][2 * i] * inv, o[db][2 * i + 1] * inv);
      int d = 32 * db + ((2 * i) & 3) + 8 * (i >> 1) + 4 * hb;
      *reinterpret_cast<unsigned*>(cp + d) = w;
    }
}

extern "C" void kernel_launch(void* const* d_in, const int* in_sizes, int n_in,
                              void* d_out, int out_size, void* d_ws, size_t ws_size,
                              hipStream_t stream) {
  const float* in_q = (const float*)d_in[0];
  const float* in_k = (const float*)d_in[1];
  const float* in_v = (const float*)d_in[2];
  const float* WQw = (const float*)d_in[3];
  const float* WQb = (const float*)d_in[4];
  const float* WKw = (const float*)d_in[5];
  const float* WKb = (const float*)d_in[6];
  const float* WVw = (const float*)d_in[7];
  const float* WVb = (const float*)d_in[8];
  const float* Ww  = (const float*)d_in[9];
  const float* Wb  = (const float*)d_in[10];
  float* out = (float*)d_out;

  constexpr size_t PROJ = (size_t)4 * 16 * 2048 * 64;  // 8,388,608 elems
  constexpr size_t WSZ = (size_t)1024 * 1024;
  const float qscale = 0.03125f * 1.4426950408889634f;  // 1/sqrt(1024) * log2(e)
  unsigned short* wsp = (unsigned short*)d_ws;

  const bool fused = ws_size >= (6 * PROJ + 4 * WSZ) * sizeof(unsigned short);

  if (fused) {
    unsigned short* Qp   = wsp;
    unsigned short* Kp   = wsp + PROJ;
    unsigned short* Vt   = wsp + 2 * PROJ;
    unsigned short* inq  = wsp + 3 * PROJ;  // later aliased as ctx
    unsigned short* ctx  = inq;
    unsigned short* ink  = wsp + 4 * PROJ;
    unsigned short* inv  = wsp + 5 * PROJ;
    unsigned short* wq16 = wsp + 6 * PROJ;
    unsigned short* wk16 = wq16 + WSZ;
    unsigned short* wv16 = wk16 + WSZ;
    unsigned short* ww16 = wv16 + WSZ;

    // weights + Q input -> bf16 (one launch)
    cvt_first_kernel<<<dim3(1024, 5), 256, 0, stream>>>(
        WQw, WKw, WVw, Ww, wq16, wk16, wv16, ww16, (int)(WSZ / 8),
        in_q, inq, (int)(PROJ / 8));
    // Q projection; cvt of K input hidden in the same dispatch
    gemm_kernel<0><<<2560, 256, 0, stream>>>(inq, wq16, WQb, Qp, 8192, 1024, 1024,
                                             qscale, 3, 512, in_k, ink, (int)(PROJ / 8));
    // K projection; cvt of V input hidden
    gemm_kernel<0><<<2560, 256, 0, stream>>>(ink, wk16, WKb, Kp, 8192, 1024, 1024,
                                             1.0f, 3, 512, in_v, inv, (int)(PROJ / 8));
    // V projection computed transposed -> V^T [B*H, 64, S]
    gemm_kernel<2><<<512, 256, 0, stream>>>(wv16, inv, WVb, Vt, 1024, 8192, 1024,
                                            1.0f, 6, 512, nullptr, nullptr, 0);
    attn7_kernel<<<1024, 256, 0, stream>>>(Qp, Kp, Vt, ctx);
    gemm_kernel<1><<<512, 256, 0, stream>>>(ctx, ww16, Wb, out, 8192, 1024, 1024,
                                            1.0f, 3, 512, nullptr, nullptr, 0);
  } else {
    // serial fallback (round-11 layout: in16 reused q->k->v, aliased as ctx)
    unsigned short* Qp   = wsp;
    unsigned short* Kp   = wsp + PROJ;
    unsigned short* Vt   = wsp + 2 * PROJ;
    unsigned short* in16 = wsp + 3 * PROJ;
    unsigned short* ctx  = in16;
    unsigned short* wq16 = wsp + 4 * PROJ;
    unsigned short* wk16 = wq16 + WSZ;
    unsigned short* wv16 = wk16 + WSZ;
    unsigned short* ww16 = wv16 + WSZ;

    cvt_first_kernel<<<dim3(1024, 5), 256, 0, stream>>>(
        WQw, WKw, WVw, Ww, wq16, wk16, wv16, ww16, (int)(WSZ / 8),
        in_q, in16, (int)(PROJ / 8));
    gemm_kernel<0><<<512, 256, 0, stream>>>(in16, wq16, WQb, Qp, 8192, 1024, 1024,
                                            qscale, 3, 512, nullptr, nullptr, 0);
    cvt1_kernel<<<2048, 256, 0, stream>>>(in_k, in16, (int)(PROJ / 8));
    gemm_kernel<0><<<512, 256, 0, stream>>>(in16, wk16, WKb, Kp, 8192, 1024, 1024,
                                            1.0f, 3, 512, nullptr, nullptr, 0);
    cvt1_kernel<<<2048, 256, 0, stream>>>(in_v, in16, (int)(PROJ / 8));
    gemm_kernel<2><<<512, 256, 0, stream>>>(wv16, in16, WVb, Vt, 1024, 8192, 1024,
                                            1.0f, 6, 512, nullptr, nullptr, 0);
    attn7_kernel<<<1024, 256, 0, stream>>>(Qp, Kp, Vt, ctx);
    gemm_kernel<1><<<512, 256, 0, stream>>>(ctx, ww16, Wb, out, 8192, 1024, 1024,
                                            1.0f, 3, 512, nullptr, nullptr, 0);
  }
}